// Round 5
// baseline (157.110 us; speedup 1.0000x reference)
//
#include <hip/hip_runtime.h>
#include <hip/hip_bf16.h>

using bf16 = __hip_bfloat16;
typedef __attribute__((ext_vector_type(4))) float f32x4;
typedef __attribute__((ext_vector_type(2))) float f32x2;
typedef __attribute__((ext_vector_type(8))) __bf16 bf16x8;
typedef __attribute__((ext_vector_type(4))) __bf16 bf16x4;

#define CIN 256
#define COUT 256
#define HW 4096
#define NB 4
#define NTOT 16384   // NB*HW
#define KDIM 2304    // CIN*9

// ---------- 1. transpose x: NCHW -> NHWC ----------
__global__ __launch_bounds__(256) void k_transpose(const float* __restrict__ x,
                                                   float* __restrict__ xt) {
  __shared__ float t[32][33];
  int bid = blockIdx.x;            // 4 * 128 * 8
  int ct = bid & 7;
  int hwt = (bid >> 3) & 127;
  int b = bid >> 10;
  int tx = threadIdx.x & 31, ty = threadIdx.x >> 5;
  int c0 = ct * 32, hw0 = hwt * 32;
  const float* xb = x + (size_t)b * CIN * HW;
#pragma unroll
  for (int i = 0; i < 32; i += 8)
    t[ty + i][tx] = xb[(size_t)(c0 + ty + i) * HW + hw0 + tx];
  __syncthreads();
  float* xo = xt + ((size_t)b * HW + hw0) * CIN + c0;
#pragma unroll
  for (int i = 0; i < 32; i += 8)
    xo[(size_t)(ty + i) * CIN + tx] = t[tx][ty + i];
}

// ---------- 2a. weight transpose for offset conv: wof[oc][c][p] -> wt[c][p][oc]
__global__ __launch_bounds__(256) void k_prepwt(const float* __restrict__ wof,
                                                float* __restrict__ wt) {
  int i = blockIdx.x * 256 + threadIdx.x;  // (c*9+p)*18 + oc, total 41472
  if (i >= 18 * CIN * 9) return;
  int oc = i % 18;
  int cp = i / 18;
  int c = cp / 9, p = cp % 9;
  wt[i] = wof[((size_t)oc * CIN + c) * 9 + p];
}

// ---------- 2b. offset conv partials: LDS-tiled, channel-chunked ----------
// grid: b(4) x rowtile(16) x cchunk(8); block = 4 rows x 64 cols
__global__ __launch_bounds__(256) void k_convoff2(const float* __restrict__ x,
                                                  const float* __restrict__ wt,
                                                  float* __restrict__ part) {
  __shared__ float lds[8][6][68];  // [ch][row][2+col], cols 1 & 66 are zero halo
  int bid = blockIdx.x;
  int chunk = bid & 7;
  int rt = (bid >> 3) & 15;
  int b = bid >> 7;
  int tid = threadIdx.x;
  int wq = tid & 63, r = tid >> 6;
  int h0 = rt * 4;
  int c0 = chunk * 32;

  // zero the halo columns once (stay zero across stages)
  if (tid < 96) {
    int cl = tid / 12, rem = tid % 12;
    lds[cl][rem >> 1][(rem & 1) ? 66 : 1] = 0.f;
  }

  float acc[18];
#pragma unroll
  for (int o = 0; o < 18; ++o) acc[o] = 0.f;

  int ch = tid >> 5, l32 = tid & 31;
  const float* xb = x + (size_t)b * CIN * HW;

  for (int cs = 0; cs < 32; cs += 8) {
    __syncthreads();
    // stage 8 channels x 6 rows x 64 cols (coalesced float2)
    const float* xp = xb + (size_t)(c0 + cs + ch) * HW;
#pragma unroll
    for (int r6 = 0; r6 < 6; ++r6) {
      int hh = h0 - 1 + r6;
      f32x2 v = {0.f, 0.f};
      if ((unsigned)hh < 64u) v = *(const f32x2*)(xp + hh * 64 + l32 * 2);
      *(f32x2*)&lds[ch][r6][2 + l32 * 2] = v;
    }
    __syncthreads();
#pragma unroll
    for (int cl = 0; cl < 8; ++cl) {
      int c = c0 + cs + cl;  // uniform
      const float* wc = wt + (size_t)c * 9 * 18;  // uniform -> s_load
      float xv[9];
#pragma unroll
      for (int ky = 0; ky < 3; ++ky)
#pragma unroll
        for (int kx = 0; kx < 3; ++kx)
          xv[ky * 3 + kx] = lds[cl][r + ky][1 + wq + kx];
#pragma unroll
      for (int p = 0; p < 9; ++p)
#pragma unroll
        for (int o = 0; o < 18; ++o)
          acc[o] = fmaf(xv[p], wc[p * 18 + o], acc[o]);
    }
  }

  float* pp = part + (size_t)chunk * (NB * 18 * HW) + (size_t)b * 18 * HW +
              (h0 + r) * 64 + wq;
#pragma unroll
  for (int o = 0; o < 18; ++o) pp[(size_t)o * HW] = acc[o];
}

// ---------- 2c. reduce channel-chunk partials + bias -> off[b][18][hw] ----------
__global__ __launch_bounds__(256) void k_offreduce(const float* __restrict__ part,
                                                   const float* __restrict__ boff,
                                                   float* __restrict__ off) {
  int i = blockIdx.x * 256 + threadIdx.x;  // f32x4 idx, total 73728
  int e0 = i * 4;
  int oc = (e0 >> 12) % 18;
  float bo = boff[oc];
  f32x4 s = {bo, bo, bo, bo};
#pragma unroll
  for (int c = 0; c < 8; ++c) s += *(const f32x4*)(part + (size_t)c * (NB * 18 * HW) + e0);
  *(f32x4*)(off + e0) = s;
}

// ---------- 3. weight prep: w[o][c][p] (f32) -> A[o][p*256+c] (bf16) ----------
__global__ __launch_bounds__(256) void k_prepw(const float* __restrict__ w,
                                               bf16* __restrict__ A) {
  int i = blockIdx.x * 256 + threadIdx.x;  // o*2304 + p*256 + c
  int o = i / KDIM, r = i % KDIM;
  int p = r >> 8, c = r & 255;
  A[i] = __float2bfloat16(w[((size_t)o * 256 + c) * 9 + p]);
}

// ---------- 4. bilinear gather -> colsT[n][p*256+c] (bf16) ----------
// one wave per n; lane = 4-channel group (f32x4 loads, bf16x4 stores)
__global__ __launch_bounds__(256) void k_gather(const float* __restrict__ xt,
                                                const float* __restrict__ off,
                                                bf16* __restrict__ colsT) {
  int tid = threadIdx.x;
  int wv = tid >> 6, l = tid & 63;
  int n = blockIdx.x * 4 + wv;
  int hw = n & 4095;
  int b = n >> 12;
  int h = hw >> 6, wq = hw & 63;
  const float* xtb = xt + (size_t)b * HW * CIN + l * 4;
  const float* offb = off + (size_t)b * 18 * HW + hw;
  bf16* outp = colsT + (size_t)n * KDIM + l * 4;
#pragma unroll
  for (int p = 0; p < 9; ++p) {
    float dy = offb[(size_t)(2 * p) * HW];
    float dx = offb[(size_t)(2 * p + 1) * HW];
    float ysf = (float)(h - 1 + p / 3) + dy;
    float xsf = (float)(wq - 1 + p % 3) + dx;
    float y0f = floorf(ysf), x0f = floorf(xsf);
    float wy1 = ysf - y0f, wx1 = xsf - x0f;
    float wy0 = 1.f - wy1, wx0 = 1.f - wx1;
    int y0 = (int)y0f, x0 = (int)x0f;
    int y1 = y0 + 1, x1 = x0 + 1;
    float w00 = wy0 * wx0, w01 = wy0 * wx1, w10 = wy1 * wx0, w11 = wy1 * wx1;
    bool vy0 = (unsigned)y0 < 64u, vy1 = (unsigned)y1 < 64u;
    bool vx0 = (unsigned)x0 < 64u, vx1 = (unsigned)x1 < 64u;
    w00 = (vy0 && vx0) ? w00 : 0.f;
    w01 = (vy0 && vx1) ? w01 : 0.f;
    w10 = (vy1 && vx0) ? w10 : 0.f;
    w11 = (vy1 && vx1) ? w11 : 0.f;
    int y0c = min(max(y0, 0), 63), y1c = min(max(y1, 0), 63);
    int x0c = min(max(x0, 0), 63), x1c = min(max(x1, 0), 63);
    f32x4 v00 = *(const f32x4*)(xtb + (size_t)(y0c * 64 + x0c) * CIN);
    f32x4 v01 = *(const f32x4*)(xtb + (size_t)(y0c * 64 + x1c) * CIN);
    f32x4 v10 = *(const f32x4*)(xtb + (size_t)(y1c * 64 + x0c) * CIN);
    f32x4 v11 = *(const f32x4*)(xtb + (size_t)(y1c * 64 + x1c) * CIN);
    f32x4 v;
#pragma unroll
    for (int k = 0; k < 4; ++k)
      v[k] = w00 * v00[k] + w01 * v01[k] + w10 * v10[k] + w11 * v11[k];
    bf16x4 o;
#pragma unroll
    for (int k = 0; k < 4; ++k) o[k] = (__bf16)v[k];
    *(bf16x4*)(outp + p * 256) = o;
  }
}

// ---------- 5. GEMM: Y[o][n] = sum_k A[o][k]*colsT[n][k] + bias[o] ----------
// BM=128, BN=128, BK=64; 256 blocks, 4 waves; LDS XOR-swizzled (T2).
// Epilogue fuses GroupNorm partial sums (atomics into gsum/gsq).
__global__ __launch_bounds__(256) void k_gemm(const bf16* __restrict__ A,
                                              const bf16* __restrict__ Bt,
                                              const float* __restrict__ bias,
                                              float* __restrict__ Y,
                                              float* __restrict__ gsum,
                                              float* __restrict__ gsq) {
  __shared__ bf16 As[2][128 * 64];  // 16 KB each
  __shared__ bf16 Bs[2][128 * 64];  // 16 KB each -> 64 KB total
  int bid = blockIdx.x;
  // bijective XCD swizzle: 256 blocks, 32 consecutive per XCD
  int swz = (bid & 7) * 32 + (bid >> 3);
  int mt = swz & 1, nt = swz >> 1;
  int m0 = mt * 128, n0 = nt * 128;
  int tid = threadIdx.x;
  int lane = tid & 63;
  int wave = tid >> 6;
  int wr = (wave >> 1) * 64, wc = (wave & 1) * 64;  // per-wave 64x64 output
  f32x4 acc[4][4];
#pragma unroll
  for (int i = 0; i < 4; ++i)
#pragma unroll
    for (int j = 0; j < 4; ++j) acc[i][j] = (f32x4){0.f, 0.f, 0.f, 0.f};

  int srow = tid >> 3;                              // 0..31
  int skdst = (tid & 7) * 8;                        // linear dest k-chunk
  int sksrc = ((tid & 7) ^ ((tid >> 3) & 7)) * 8;   // pre-swizzled source (T2)
  auto stage = [&](int buf, int k0) {
#pragma unroll
    for (int ps = 0; ps < 4; ++ps) {
      int r = srow + ps * 32;
      __builtin_amdgcn_global_load_lds(
          (const __attribute__((address_space(1))) void*)(A + (size_t)(m0 + r) * KDIM + k0 + sksrc),
          (__attribute__((address_space(3))) void*)(&As[buf][r * 64 + skdst]), 16, 0, 0);
    }
#pragma unroll
    for (int ps = 0; ps < 4; ++ps) {
      int r = srow + ps * 32;
      __builtin_amdgcn_global_load_lds(
          (const __attribute__((address_space(1))) void*)(Bt + (size_t)(n0 + r) * KDIM + k0 + sksrc),
          (__attribute__((address_space(3))) void*)(&Bs[buf][r * 64 + skdst]), 16, 0, 0);
    }
  };

  stage(0, 0);
  int rl = lane & 15;
  int kb = (lane >> 4) * 8;
  int xorv = (rl & 7) * 8;  // read-side XOR (row&7)*8 elements; row&7 == rl&7
  for (int kt = 0; kt < KDIM / 64; ++kt) {
    __syncthreads();  // drains vmcnt -> buf[kt&1] ready; all prev reads done
    if (kt + 1 < KDIM / 64) stage((kt + 1) & 1, (kt + 1) * 64);
    const bf16* as = As[kt & 1];
    const bf16* bs = Bs[kt & 1];
#pragma unroll
    for (int kh = 0; kh < 2; ++kh) {
      int kc = (kh * 32 + kb) ^ xorv;
      bf16x8 af[4], bfr[4];
#pragma unroll
      for (int i = 0; i < 4; ++i)
        af[i] = *(const bf16x8*)(as + (wr + i * 16 + rl) * 64 + kc);
#pragma unroll
      for (int j = 0; j < 4; ++j)
        bfr[j] = *(const bf16x8*)(bs + (wc + j * 16 + rl) * 64 + kc);
#pragma unroll
      for (int i = 0; i < 4; ++i)
#pragma unroll
        for (int j = 0; j < 4; ++j)
          acc[i][j] = __builtin_amdgcn_mfma_f32_16x16x32_bf16(af[i], bfr[j], acc[i][j], 0, 0, 0);
    }
  }
  // epilogue: C/D layout col=lane&15, row=(lane>>4)*4+r. Fused GN partials.
  int cl = lane & 15, rg = (lane >> 4) * 4;
  int b = n0 >> 12;  // BN=128 n-tile lies within one image
#pragma unroll
  for (int i = 0; i < 4; ++i) {
    int obase = m0 + wr + i * 16;      // multiple of 16, group-aligned
    int ob = obase + rg;
    float s = 0.f, s2 = 0.f;
#pragma unroll
    for (int j = 0; j < 4; ++j) {
      int nn = n0 + wc + j * 16 + cl;
#pragma unroll
      for (int r = 0; r < 4; ++r) {
        float yv = acc[i][j][r] + bias[ob + r];
        Y[(size_t)(ob + r) * NTOT + nn] = yv;
        s += yv;
        s2 = fmaf(yv, yv, s2);
      }
    }
    // reduce within each 32-lane half (covers one 8-ch group each)
#pragma unroll
    for (int mk = 1; mk <= 16; mk <<= 1) {
      s += __shfl_xor(s, mk);
      s2 += __shfl_xor(s2, mk);
    }
    if ((lane & 31) == 0) {
      int g = (obase >> 3) + (lane >> 5);
      atomicAdd(&gsum[b * 32 + g], s);
      atomicAdd(&gsq[b * 32 + g], s2);
    }
  }
}

// ---------- 6. apply norm + relu, write out[b][o][hw] (stats inline) ----------
__global__ __launch_bounds__(256) void k_apply(const float* __restrict__ Y,
                                               const float* __restrict__ gsum,
                                               const float* __restrict__ gsq,
                                               const float* __restrict__ gamma,
                                               const float* __restrict__ beta,
                                               float* __restrict__ out) {
  int i = blockIdx.x * 256 + threadIdx.x;  // vec4 id, 1048576 total
  int hw4 = i & 1023;
  int o = (i >> 10) & 255;
  int b = i >> 18;
  int g = o >> 3;
  float mu = gsum[b * 32 + g] * (1.f / 32768.f);
  float var = gsq[b * 32 + g] * (1.f / 32768.f) - mu * mu;
  float rs = rsqrtf(var + 1e-5f);
  float s = rs * gamma[o];
  float t = beta[o] - mu * s;
  f32x4 v = *(const f32x4*)(Y + (size_t)o * NTOT + b * HW + hw4 * 4);
  f32x4 r;
#pragma unroll
  for (int k = 0; k < 4; ++k) r[k] = fmaxf(v[k] * s + t, 0.f);
  *(f32x4*)(out + (size_t)i * 4) = r;
}

extern "C" void kernel_launch(void* const* d_in, const int* in_sizes, int n_in,
                              void* d_out, int out_size, void* d_ws, size_t ws_size,
                              hipStream_t stream) {
  const float* x = (const float*)d_in[0];
  const float* w_off = (const float*)d_in[1];
  const float* b_off = (const float*)d_in[2];
  const float* w = (const float*)d_in[3];
  const float* bias = (const float*)d_in[4];
  const float* gamma = (const float*)d_in[5];
  const float* beta = (const float*)d_in[6];
  float* out = (float*)d_out;
  char* ws = (char*)d_ws;

  float* xt = (float*)(ws);                                  // 16,777,216 B
  float* offb = (float*)(ws + 16777216);                     //  1,179,648 B
  bf16* Abf = (bf16*)(ws + 16777216 + 1179648);              //  1,179,648 B
  bf16* colsT = (bf16*)(ws + 16777216 + 2 * 1179648);        // 75,497,472 B
  float* Y = (float*)(ws + 16777216 + 2 * 1179648 + 75497472);  // 16,777,216 B
  float* gsum = (float*)(ws + 2 * 16777216 + 2 * 1179648 + 75497472);  // 512 B
  float* gsq = gsum + 128;                                             // 512 B

  // scratch for the offset conv, aliased into the colsT region (dead until
  // k_gather, which runs after k_offreduce and fully overwrites it)
  float* wt = (float*)colsT;                       // 165,888 B
  float* part = (float*)((char*)colsT + 262144);   // 9,437,184 B

  hipMemsetAsync(gsum, 0, 2 * 128 * sizeof(float), stream);
  k_transpose<<<4096, 256, 0, stream>>>(x, xt);
  k_prepwt<<<162, 256, 0, stream>>>(w_off, wt);
  k_convoff2<<<512, 256, 0, stream>>>(x, wt, part);
  k_offreduce<<<288, 256, 0, stream>>>(part, b_off, offb);
  k_prepw<<<2304, 256, 0, stream>>>(w, Abf);
  k_gather<<<4096, 256, 0, stream>>>(xt, offb, colsT);
  k_gemm<<<256, 256, 0, stream>>>(Abf, colsT, bias, Y, gsum, gsq);
  k_apply<<<4096, 256, 0, stream>>>(Y, gsum, gsq, gamma, beta, out);
}

// Round 6
// 146.206 us; speedup vs baseline: 1.0746x; 1.0746x over previous
//
#include <hip/hip_runtime.h>
#include <hip/hip_bf16.h>

using bf16 = __hip_bfloat16;
typedef __attribute__((ext_vector_type(4))) float f32x4;
typedef __attribute__((ext_vector_type(2))) float f32x2;
typedef __attribute__((ext_vector_type(8))) __bf16 bf16x8;
typedef __attribute__((ext_vector_type(4))) __bf16 bf16x4;

#define CIN 256
#define COUT 256
#define HW 4096
#define NB 4
#define NTOT 16384   // NB*HW
#define KDIM 2304    // CIN*9

// ---------- 1. transpose x: NCHW -> NHWC ----------
__global__ __launch_bounds__(256) void k_transpose(const float* __restrict__ x,
                                                   float* __restrict__ xt) {
  __shared__ float t[32][33];
  int bid = blockIdx.x;            // 4 * 128 * 8
  int ct = bid & 7;
  int hwt = (bid >> 3) & 127;
  int b = bid >> 10;
  int tx = threadIdx.x & 31, ty = threadIdx.x >> 5;
  int c0 = ct * 32, hw0 = hwt * 32;
  const float* xb = x + (size_t)b * CIN * HW;
#pragma unroll
  for (int i = 0; i < 32; i += 8)
    t[ty + i][tx] = xb[(size_t)(c0 + ty + i) * HW + hw0 + tx];
  __syncthreads();
  float* xo = xt + ((size_t)b * HW + hw0) * CIN + c0;
#pragma unroll
  for (int i = 0; i < 32; i += 8)
    xo[(size_t)(ty + i) * CIN + tx] = t[tx][ty + i];
}

// ---------- 2a. weight transpose for offset conv: wof[oc][c][p] -> wt[c][p][oc]
__global__ __launch_bounds__(256) void k_prepwt(const float* __restrict__ wof,
                                                float* __restrict__ wt) {
  int i = blockIdx.x * 256 + threadIdx.x;  // (c*9+p)*18 + oc, total 41472
  if (i >= 18 * CIN * 9) return;
  int oc = i % 18;
  int cp = i / 18;
  int c = cp / 9, p = cp % 9;
  wt[i] = wof[((size_t)oc * CIN + c) * 9 + p];
}

// ---------- 2b. offset conv partials: LDS-tiled, channel-chunked ----------
// grid: b(4) x rowtile(16) x cchunk(8); block = 4 rows x 64 cols
__global__ __launch_bounds__(256) void k_convoff2(const float* __restrict__ x,
                                                  const float* __restrict__ wt,
                                                  float* __restrict__ part) {
  __shared__ float lds[8][6][68];  // [ch][row][2+col], cols 1 & 66 are zero halo
  int bid = blockIdx.x;
  int chunk = bid & 7;
  int rt = (bid >> 3) & 15;
  int b = bid >> 7;
  int tid = threadIdx.x;
  int wq = tid & 63, r = tid >> 6;
  int h0 = rt * 4;
  int c0 = chunk * 32;

  // zero the halo columns once (stay zero across stages)
  if (tid < 96) {
    int cl = tid / 12, rem = tid % 12;
    lds[cl][rem >> 1][(rem & 1) ? 66 : 1] = 0.f;
  }

  float acc[18];
#pragma unroll
  for (int o = 0; o < 18; ++o) acc[o] = 0.f;

  int ch = tid >> 5, l32 = tid & 31;
  const float* xb = x + (size_t)b * CIN * HW;

  for (int cs = 0; cs < 32; cs += 8) {
    __syncthreads();
    // stage 8 channels x 6 rows x 64 cols (coalesced float2)
    const float* xp = xb + (size_t)(c0 + cs + ch) * HW;
#pragma unroll
    for (int r6 = 0; r6 < 6; ++r6) {
      int hh = h0 - 1 + r6;
      f32x2 v = {0.f, 0.f};
      if ((unsigned)hh < 64u) v = *(const f32x2*)(xp + hh * 64 + l32 * 2);
      *(f32x2*)&lds[ch][r6][2 + l32 * 2] = v;
    }
    __syncthreads();
#pragma unroll
    for (int cl = 0; cl < 8; ++cl) {
      int c = c0 + cs + cl;  // uniform
      const float* wc = wt + (size_t)c * 9 * 18;  // uniform -> s_load
      float xv[9];
#pragma unroll
      for (int ky = 0; ky < 3; ++ky)
#pragma unroll
        for (int kx = 0; kx < 3; ++kx)
          xv[ky * 3 + kx] = lds[cl][r + ky][1 + wq + kx];
#pragma unroll
      for (int p = 0; p < 9; ++p)
#pragma unroll
        for (int o = 0; o < 18; ++o)
          acc[o] = fmaf(xv[p], wc[p * 18 + o], acc[o]);
    }
  }

  float* pp = part + (size_t)chunk * (NB * 18 * HW) + (size_t)b * 18 * HW +
              (h0 + r) * 64 + wq;
#pragma unroll
  for (int o = 0; o < 18; ++o) pp[(size_t)o * HW] = acc[o];
}

// ---------- 2c. reduce channel-chunk partials + bias -> off[b][18][hw] ----------
__global__ __launch_bounds__(256) void k_offreduce(const float* __restrict__ part,
                                                   const float* __restrict__ boff,
                                                   float* __restrict__ off) {
  int i = blockIdx.x * 256 + threadIdx.x;  // f32x4 idx, total 73728
  int e0 = i * 4;
  int oc = (e0 >> 12) % 18;
  float bo = boff[oc];
  f32x4 s = {bo, bo, bo, bo};
#pragma unroll
  for (int c = 0; c < 8; ++c) s += *(const f32x4*)(part + (size_t)c * (NB * 18 * HW) + e0);
  *(f32x4*)(off + e0) = s;
}

// ---------- 3. weight prep: w[o][c][p] (f32) -> packed MFMA A-frags (bf16) ----
// Apk[((f*72 + ktg)*64 + lane)*8 + e] = A[o = f*16 + (lane&15)]
//                                        [k = ktg*32 + (lane>>4)*8 + e]
// where k = p*256 + c. A wave's fragment load = 64 lanes x 16B contiguous.
__global__ __launch_bounds__(256) void k_prepw(const float* __restrict__ w,
                                               bf16* __restrict__ Apk) {
  int j = blockIdx.x * 256 + threadIdx.x;  // 589824 total
  int e = j & 7;
  int l = (j >> 3) & 63;
  int rem = j >> 9;
  int ktg = rem % 72;
  int f = rem / 72;
  int o = f * 16 + (l & 15);
  int k = ktg * 32 + ((l >> 4) << 3) + e;
  int p = k >> 8, c = k & 255;
  Apk[j] = __float2bfloat16(w[((size_t)o * 256 + c) * 9 + p]);
}

// ---------- 4. bilinear gather -> colsT[n][p*256+c] (bf16) ----------
// one wave per n; lane = 4-channel group (f32x4 loads, bf16x4 stores)
__global__ __launch_bounds__(256) void k_gather(const float* __restrict__ xt,
                                                const float* __restrict__ off,
                                                bf16* __restrict__ colsT) {
  int tid = threadIdx.x;
  int wv = tid >> 6, l = tid & 63;
  int n = blockIdx.x * 4 + wv;
  int hw = n & 4095;
  int b = n >> 12;
  int h = hw >> 6, wq = hw & 63;
  const float* xtb = xt + (size_t)b * HW * CIN + l * 4;
  const float* offb = off + (size_t)b * 18 * HW + hw;
  bf16* outp = colsT + (size_t)n * KDIM + l * 4;
#pragma unroll
  for (int p = 0; p < 9; ++p) {
    float dy = offb[(size_t)(2 * p) * HW];
    float dx = offb[(size_t)(2 * p + 1) * HW];
    float ysf = (float)(h - 1 + p / 3) + dy;
    float xsf = (float)(wq - 1 + p % 3) + dx;
    float y0f = floorf(ysf), x0f = floorf(xsf);
    float wy1 = ysf - y0f, wx1 = xsf - x0f;
    float wy0 = 1.f - wy1, wx0 = 1.f - wx1;
    int y0 = (int)y0f, x0 = (int)x0f;
    int y1 = y0 + 1, x1 = x0 + 1;
    float w00 = wy0 * wx0, w01 = wy0 * wx1, w10 = wy1 * wx0, w11 = wy1 * wx1;
    bool vy0 = (unsigned)y0 < 64u, vy1 = (unsigned)y1 < 64u;
    bool vx0 = (unsigned)x0 < 64u, vx1 = (unsigned)x1 < 64u;
    w00 = (vy0 && vx0) ? w00 : 0.f;
    w01 = (vy0 && vx1) ? w01 : 0.f;
    w10 = (vy1 && vx0) ? w10 : 0.f;
    w11 = (vy1 && vx1) ? w11 : 0.f;
    int y0c = min(max(y0, 0), 63), y1c = min(max(y1, 0), 63);
    int x0c = min(max(x0, 0), 63), x1c = min(max(x1, 0), 63);
    f32x4 v00 = *(const f32x4*)(xtb + (size_t)(y0c * 64 + x0c) * CIN);
    f32x4 v01 = *(const f32x4*)(xtb + (size_t)(y0c * 64 + x1c) * CIN);
    f32x4 v10 = *(const f32x4*)(xtb + (size_t)(y1c * 64 + x0c) * CIN);
    f32x4 v11 = *(const f32x4*)(xtb + (size_t)(y1c * 64 + x1c) * CIN);
    f32x4 v;
#pragma unroll
    for (int k = 0; k < 4; ++k)
      v[k] = w00 * v00[k] + w01 * v01[k] + w10 * v10[k] + w11 * v11[k];
    bf16x4 o;
#pragma unroll
    for (int k = 0; k < 4; ++k) o[k] = (__bf16)v[k];
    *(bf16x4*)(outp + p * 256) = o;
  }
}

// ---------- 5. GEMM: Y[o][n] = sum_k A[o][k]*colsT[n][k] + bias[o] ----------
// BM=128, BN=64, BK=64; 512 blocks (2/CU), 4 waves. B in LDS (XOR-swizzled),
// A direct from L2 via packed fragments, register-double-buffered prefetch.
// Epilogue fuses GroupNorm partial sums (atomics into gsum/gsq).
__global__ __launch_bounds__(256) void k_gemm(const bf16* __restrict__ Apk,
                                              const bf16* __restrict__ Bt,
                                              const float* __restrict__ bias,
                                              float* __restrict__ Y,
                                              float* __restrict__ gsum,
                                              float* __restrict__ gsq) {
  __shared__ bf16 Bs[2][64 * 64];   // 8 KB each -> 16 KB total
  int bid = blockIdx.x;
  // bijective XCD swizzle: 512 blocks, 64 consecutive per XCD
  int swz = (bid & 7) * 64 + (bid >> 3);
  int mt = swz & 1, nt = swz >> 1;
  int m0 = mt * 128, n0 = nt * 64;
  int tid = threadIdx.x;
  int lane = tid & 63;
  int wave = tid >> 6;
  int wr = (wave >> 1) * 64, wc = (wave & 1) * 32;  // per-wave 64x32 output
  f32x4 acc[4][2];
#pragma unroll
  for (int i = 0; i < 4; ++i)
#pragma unroll
    for (int j = 0; j < 2; ++j) acc[i][j] = (f32x4){0.f, 0.f, 0.f, 0.f};

  int srow = tid >> 3;                              // 0..31
  int skdst = (tid & 7) * 8;                        // linear dest k-chunk
  int sksrc = ((tid & 7) ^ ((tid >> 3) & 7)) * 8;   // pre-swizzled source (T2)
  auto stage = [&](int buf, int k0) {
#pragma unroll
    for (int ps = 0; ps < 2; ++ps) {
      int r = srow + ps * 32;
      __builtin_amdgcn_global_load_lds(
          (const __attribute__((address_space(1))) void*)(Bt + (size_t)(n0 + r) * KDIM + k0 + sksrc),
          (__attribute__((address_space(3))) void*)(&Bs[buf][r * 64 + skdst]), 16, 0, 0);
    }
  };

  int fbase = (m0 + wr) >> 4;  // A fragment row-block base for this wave
  auto loadA = [&](bf16x8 (&dst)[2][4], int kt) {
#pragma unroll
    for (int kh = 0; kh < 2; ++kh)
#pragma unroll
      for (int i = 0; i < 4; ++i)
        dst[kh][i] = *(const bf16x8*)(Apk +
            ((size_t)((fbase + i) * 72 + kt * 2 + kh) * 64 + lane) * 8);
  };

  constexpr int NT = KDIM / 64;  // 36
  bf16x8 aA[2][4], aB[2][4];
  loadA(aA, 0);
  stage(0, 0);
  int rl = lane & 15;
  int kb = (lane >> 4) * 8;
  int xorv = (rl & 7) * 8;  // read-side XOR (row&7)*8 elements; row&7 == rl&7

  auto step = [&](int kt, bf16x8 (&cur)[2][4], bf16x8 (&nxt)[2][4], int buf) {
    __syncthreads();  // drains vmcnt: Bs[buf] + cur A-frags all ready
    if (kt + 1 < NT) {
      stage(buf ^ 1, (kt + 1) * 64);
      loadA(nxt, kt + 1);  // in flight until next barrier
    }
    const bf16* bs = Bs[buf];
#pragma unroll
    for (int kh = 0; kh < 2; ++kh) {
      int kc = (kh * 32 + kb) ^ xorv;
      bf16x8 bfr[2];
#pragma unroll
      for (int j = 0; j < 2; ++j)
        bfr[j] = *(const bf16x8*)(bs + (wc + j * 16 + rl) * 64 + kc);
#pragma unroll
      for (int i = 0; i < 4; ++i)
#pragma unroll
        for (int j = 0; j < 2; ++j)
          acc[i][j] = __builtin_amdgcn_mfma_f32_16x16x32_bf16(cur[kh][i], bfr[j], acc[i][j], 0, 0, 0);
    }
  };

  for (int kt2 = 0; kt2 < NT; kt2 += 2) {
    step(kt2, aA, aB, 0);
    step(kt2 + 1, aB, aA, 1);
  }

  // epilogue: C/D layout col=lane&15, row=(lane>>4)*4+r. Fused GN partials.
  int cl = lane & 15, rg = (lane >> 4) * 4;
  int b = n0 >> 12;  // BN=64 n-tile lies within one image
#pragma unroll
  for (int i = 0; i < 4; ++i) {
    int obase = m0 + wr + i * 16;      // multiple of 16, group-aligned
    int ob = obase + rg;
    float s = 0.f, s2 = 0.f;
#pragma unroll
    for (int j = 0; j < 2; ++j) {
      int nn = n0 + wc + j * 16 + cl;
#pragma unroll
      for (int r = 0; r < 4; ++r) {
        float yv = acc[i][j][r] + bias[ob + r];
        Y[(size_t)(ob + r) * NTOT + nn] = yv;
        s += yv;
        s2 = fmaf(yv, yv, s2);
      }
    }
    // reduce within each 32-lane half (covers one 8-ch group each)
#pragma unroll
    for (int mk = 1; mk <= 16; mk <<= 1) {
      s += __shfl_xor(s, mk);
      s2 += __shfl_xor(s2, mk);
    }
    if ((lane & 31) == 0) {
      int g = (obase >> 3) + (lane >> 5);
      atomicAdd(&gsum[b * 32 + g], s);
      atomicAdd(&gsq[b * 32 + g], s2);
    }
  }
}

// ---------- 6. apply norm + relu, write out[b][o][hw] (stats inline) ----------
__global__ __launch_bounds__(256) void k_apply(const float* __restrict__ Y,
                                               const float* __restrict__ gsum,
                                               const float* __restrict__ gsq,
                                               const float* __restrict__ gamma,
                                               const float* __restrict__ beta,
                                               float* __restrict__ out) {
  int i = blockIdx.x * 256 + threadIdx.x;  // vec4 id, 1048576 total
  int hw4 = i & 1023;
  int o = (i >> 10) & 255;
  int b = i >> 18;
  int g = o >> 3;
  float mu = gsum[b * 32 + g] * (1.f / 32768.f);
  float var = gsq[b * 32 + g] * (1.f / 32768.f) - mu * mu;
  float rs = rsqrtf(var + 1e-5f);
  float s = rs * gamma[o];
  float t = beta[o] - mu * s;
  f32x4 v = *(const f32x4*)(Y + (size_t)o * NTOT + b * HW + hw4 * 4);
  f32x4 r;
#pragma unroll
  for (int k = 0; k < 4; ++k) r[k] = fmaxf(v[k] * s + t, 0.f);
  *(f32x4*)(out + (size_t)i * 4) = r;
}

extern "C" void kernel_launch(void* const* d_in, const int* in_sizes, int n_in,
                              void* d_out, int out_size, void* d_ws, size_t ws_size,
                              hipStream_t stream) {
  const float* x = (const float*)d_in[0];
  const float* w_off = (const float*)d_in[1];
  const float* b_off = (const float*)d_in[2];
  const float* w = (const float*)d_in[3];
  const float* bias = (const float*)d_in[4];
  const float* gamma = (const float*)d_in[5];
  const float* beta = (const float*)d_in[6];
  float* out = (float*)d_out;
  char* ws = (char*)d_ws;

  float* xt = (float*)(ws);                                  // 16,777,216 B
  float* offb = (float*)(ws + 16777216);                     //  1,179,648 B
  bf16* Abf = (bf16*)(ws + 16777216 + 1179648);              //  1,179,648 B
  bf16* colsT = (bf16*)(ws + 16777216 + 2 * 1179648);        // 75,497,472 B
  float* Y = (float*)(ws + 16777216 + 2 * 1179648 + 75497472);  // 16,777,216 B
  float* gsum = (float*)(ws + 2 * 16777216 + 2 * 1179648 + 75497472);  // 512 B
  float* gsq = gsum + 128;                                             // 512 B

  // scratch for the offset conv, aliased into the colsT region (dead until
  // k_gather, which runs after k_offreduce and fully overwrites it)
  float* wt = (float*)colsT;                       // 165,888 B
  float* part = (float*)((char*)colsT + 262144);   // 9,437,184 B

  hipMemsetAsync(gsum, 0, 2 * 128 * sizeof(float), stream);
  k_transpose<<<4096, 256, 0, stream>>>(x, xt);
  k_prepwt<<<162, 256, 0, stream>>>(w_off, wt);
  k_convoff2<<<512, 256, 0, stream>>>(x, wt, part);
  k_offreduce<<<288, 256, 0, stream>>>(part, b_off, offb);
  k_prepw<<<2304, 256, 0, stream>>>(w, Abf);
  k_gather<<<4096, 256, 0, stream>>>(xt, offb, colsT);
  k_gemm<<<512, 256, 0, stream>>>(Abf, colsT, bias, Y, gsum, gsq);
  k_apply<<<4096, 256, 0, stream>>>(Y, gsum, gsq, gamma, beta, out);
}

// Round 7
// 142.823 us; speedup vs baseline: 1.1000x; 1.0237x over previous
//
#include <hip/hip_runtime.h>
#include <hip/hip_bf16.h>

using bf16 = __hip_bfloat16;
typedef __attribute__((ext_vector_type(4))) float f32x4;
typedef __attribute__((ext_vector_type(2))) float f32x2;
typedef __attribute__((ext_vector_type(8))) __bf16 bf16x8;
typedef __attribute__((ext_vector_type(4))) __bf16 bf16x4;

#define CIN 256
#define COUT 256
#define HW 4096
#define NB 4
#define NTOT 16384   // NB*HW
#define KDIM 2304    // CIN*9

// ---------- 1. transpose x: NCHW -> NHWC ----------
__global__ __launch_bounds__(256) void k_transpose(const float* __restrict__ x,
                                                   float* __restrict__ xt) {
  __shared__ float t[32][33];
  int bid = blockIdx.x;            // 4 * 128 * 8
  int ct = bid & 7;
  int hwt = (bid >> 3) & 127;
  int b = bid >> 10;
  int tx = threadIdx.x & 31, ty = threadIdx.x >> 5;
  int c0 = ct * 32, hw0 = hwt * 32;
  const float* xb = x + (size_t)b * CIN * HW;
#pragma unroll
  for (int i = 0; i < 32; i += 8)
    t[ty + i][tx] = xb[(size_t)(c0 + ty + i) * HW + hw0 + tx];
  __syncthreads();
  float* xo = xt + ((size_t)b * HW + hw0) * CIN + c0;
#pragma unroll
  for (int i = 0; i < 32; i += 8)
    xo[(size_t)(ty + i) * CIN + tx] = t[tx][ty + i];
}

// ---------- 2a. weight transpose for offset conv: wof[oc][c][p] -> wt[c][p][oc]
__global__ __launch_bounds__(256) void k_prepwt(const float* __restrict__ wof,
                                                float* __restrict__ wt) {
  int i = blockIdx.x * 256 + threadIdx.x;  // (c*9+p)*18 + oc, total 41472
  if (i >= 18 * CIN * 9) return;
  int oc = i % 18;
  int cp = i / 18;
  int c = cp / 9, p = cp % 9;
  wt[i] = wof[((size_t)oc * CIN + c) * 9 + p];
}

// ---------- 2b. offset conv partials: LDS-tiled, channel-chunked ----------
// grid: b(4) x rowtile(16) x cchunk(8); block = 4 rows x 64 cols
__global__ __launch_bounds__(256) void k_convoff2(const float* __restrict__ x,
                                                  const float* __restrict__ wt,
                                                  float* __restrict__ part) {
  __shared__ float lds[8][6][68];  // [ch][row][2+col], cols 1 & 66 are zero halo
  int bid = blockIdx.x;
  int chunk = bid & 7;
  int rt = (bid >> 3) & 15;
  int b = bid >> 7;
  int tid = threadIdx.x;
  int wq = tid & 63, r = tid >> 6;
  int h0 = rt * 4;
  int c0 = chunk * 32;

  // zero the halo columns once (stay zero across stages)
  if (tid < 96) {
    int cl = tid / 12, rem = tid % 12;
    lds[cl][rem >> 1][(rem & 1) ? 66 : 1] = 0.f;
  }

  float acc[18];
#pragma unroll
  for (int o = 0; o < 18; ++o) acc[o] = 0.f;

  int ch = tid >> 5, l32 = tid & 31;
  const float* xb = x + (size_t)b * CIN * HW;

  for (int cs = 0; cs < 32; cs += 8) {
    __syncthreads();
    // stage 8 channels x 6 rows x 64 cols (coalesced float2)
    const float* xp = xb + (size_t)(c0 + cs + ch) * HW;
#pragma unroll
    for (int r6 = 0; r6 < 6; ++r6) {
      int hh = h0 - 1 + r6;
      f32x2 v = {0.f, 0.f};
      if ((unsigned)hh < 64u) v = *(const f32x2*)(xp + hh * 64 + l32 * 2);
      *(f32x2*)&lds[ch][r6][2 + l32 * 2] = v;
    }
    __syncthreads();
#pragma unroll
    for (int cl = 0; cl < 8; ++cl) {
      int c = c0 + cs + cl;  // uniform
      const float* wc = wt + (size_t)c * 9 * 18;  // uniform -> s_load
      float xv[9];
#pragma unroll
      for (int ky = 0; ky < 3; ++ky)
#pragma unroll
        for (int kx = 0; kx < 3; ++kx)
          xv[ky * 3 + kx] = lds[cl][r + ky][1 + wq + kx];
#pragma unroll
      for (int p = 0; p < 9; ++p)
#pragma unroll
        for (int o = 0; o < 18; ++o)
          acc[o] = fmaf(xv[p], wc[p * 18 + o], acc[o]);
    }
  }

  float* pp = part + (size_t)chunk * (NB * 18 * HW) + (size_t)b * 18 * HW +
              (h0 + r) * 64 + wq;
#pragma unroll
  for (int o = 0; o < 18; ++o) pp[(size_t)o * HW] = acc[o];
}

// ---------- 2c. reduce channel-chunk partials + bias -> off[b][18][hw] ----------
__global__ __launch_bounds__(256) void k_offreduce(const float* __restrict__ part,
                                                   const float* __restrict__ boff,
                                                   float* __restrict__ off) {
  int i = blockIdx.x * 256 + threadIdx.x;  // f32x4 idx, total 73728
  int e0 = i * 4;
  int oc = (e0 >> 12) % 18;
  float bo = boff[oc];
  f32x4 s = {bo, bo, bo, bo};
#pragma unroll
  for (int c = 0; c < 8; ++c) s += *(const f32x4*)(part + (size_t)c * (NB * 18 * HW) + e0);
  *(f32x4*)(off + e0) = s;
}

// ---------- 3. weight prep: w[o][c][p] (f32) -> A[o][p*256+c] (bf16) ----------
__global__ __launch_bounds__(256) void k_prepw(const float* __restrict__ w,
                                               bf16* __restrict__ A) {
  int i = blockIdx.x * 256 + threadIdx.x;  // o*2304 + p*256 + c
  int o = i / KDIM, r = i % KDIM;
  int p = r >> 8, c = r & 255;
  A[i] = __float2bfloat16(w[((size_t)o * 256 + c) * 9 + p]);
}

// ---------- 4. bilinear gather -> colsT[n][p*256+c] (bf16) ----------
// one wave per n; lane = 4-channel group (f32x4 loads, bf16x4 stores)
__global__ __launch_bounds__(256) void k_gather(const float* __restrict__ xt,
                                                const float* __restrict__ off,
                                                bf16* __restrict__ colsT) {
  int tid = threadIdx.x;
  int wv = tid >> 6, l = tid & 63;
  int n = blockIdx.x * 4 + wv;
  int hw = n & 4095;
  int b = n >> 12;
  int h = hw >> 6, wq = hw & 63;
  const float* xtb = xt + (size_t)b * HW * CIN + l * 4;
  const float* offb = off + (size_t)b * 18 * HW + hw;
  bf16* outp = colsT + (size_t)n * KDIM + l * 4;
#pragma unroll
  for (int p = 0; p < 9; ++p) {
    float dy = offb[(size_t)(2 * p) * HW];
    float dx = offb[(size_t)(2 * p + 1) * HW];
    float ysf = (float)(h - 1 + p / 3) + dy;
    float xsf = (float)(wq - 1 + p % 3) + dx;
    float y0f = floorf(ysf), x0f = floorf(xsf);
    float wy1 = ysf - y0f, wx1 = xsf - x0f;
    float wy0 = 1.f - wy1, wx0 = 1.f - wx1;
    int y0 = (int)y0f, x0 = (int)x0f;
    int y1 = y0 + 1, x1 = x0 + 1;
    float w00 = wy0 * wx0, w01 = wy0 * wx1, w10 = wy1 * wx0, w11 = wy1 * wx1;
    bool vy0 = (unsigned)y0 < 64u, vy1 = (unsigned)y1 < 64u;
    bool vx0 = (unsigned)x0 < 64u, vx1 = (unsigned)x1 < 64u;
    w00 = (vy0 && vx0) ? w00 : 0.f;
    w01 = (vy0 && vx1) ? w01 : 0.f;
    w10 = (vy1 && vx0) ? w10 : 0.f;
    w11 = (vy1 && vx1) ? w11 : 0.f;
    int y0c = min(max(y0, 0), 63), y1c = min(max(y1, 0), 63);
    int x0c = min(max(x0, 0), 63), x1c = min(max(x1, 0), 63);
    f32x4 v00 = *(const f32x4*)(xtb + (size_t)(y0c * 64 + x0c) * CIN);
    f32x4 v01 = *(const f32x4*)(xtb + (size_t)(y0c * 64 + x1c) * CIN);
    f32x4 v10 = *(const f32x4*)(xtb + (size_t)(y1c * 64 + x0c) * CIN);
    f32x4 v11 = *(const f32x4*)(xtb + (size_t)(y1c * 64 + x1c) * CIN);
    f32x4 v;
#pragma unroll
    for (int k = 0; k < 4; ++k)
      v[k] = w00 * v00[k] + w01 * v01[k] + w10 * v10[k] + w11 * v11[k];
    bf16x4 o;
#pragma unroll
    for (int k = 0; k < 4; ++k) o[k] = (__bf16)v[k];
    *(bf16x4*)(outp + p * 256) = o;
  }
}

// ---------- 5. GEMM: Y[o][n] = sum_k A[o][k]*colsT[n][k] + bias[o] ----------
// BM=128, BN=64, BK=64; 512 blocks (2/CU), 4 waves; LDS XOR-swizzled (T2).
// 3-deep LDS ring + counted s_waitcnt vmcnt(6) (T4): loads span 2 iterations,
// raw s_barrier never drains the VMEM queue. Fused GN partial sums.
__global__ __launch_bounds__(256) void k_gemm(const bf16* __restrict__ A,
                                              const bf16* __restrict__ Bt,
                                              const float* __restrict__ bias,
                                              float* __restrict__ Y,
                                              float* __restrict__ gsum,
                                              float* __restrict__ gsq) {
  __shared__ bf16 As[3][128 * 64];  // 16 KB each
  __shared__ bf16 Bs[3][64 * 64];   //  8 KB each  -> 72 KB total
  int bid = blockIdx.x;
  // bijective XCD swizzle: 512 blocks, 64 consecutive per XCD
  int swz = (bid & 7) * 64 + (bid >> 3);
  int mt = swz & 1, nt = swz >> 1;
  int m0 = mt * 128, n0 = nt * 64;
  int tid = threadIdx.x;
  int lane = tid & 63;
  int wave = tid >> 6;
  int wr = (wave >> 1) * 64, wc = (wave & 1) * 32;  // per-wave 64x32 output
  f32x4 acc[4][2];
#pragma unroll
  for (int i = 0; i < 4; ++i)
#pragma unroll
    for (int j = 0; j < 2; ++j) acc[i][j] = (f32x4){0.f, 0.f, 0.f, 0.f};

  int srow = tid >> 3;                              // 0..31
  int skdst = (tid & 7) * 8;                        // linear dest k-chunk
  int sksrc = ((tid & 7) ^ ((tid >> 3) & 7)) * 8;   // pre-swizzled source (T2)
  auto stage = [&](int buf, int kt) {               // 6 loads/thread
    int k0 = kt * 64;
#pragma unroll
    for (int ps = 0; ps < 4; ++ps) {
      int r = srow + ps * 32;
      __builtin_amdgcn_global_load_lds(
          (const __attribute__((address_space(1))) void*)(A + (size_t)(m0 + r) * KDIM + k0 + sksrc),
          (__attribute__((address_space(3))) void*)(&As[buf][r * 64 + skdst]), 16, 0, 0);
    }
#pragma unroll
    for (int ps = 0; ps < 2; ++ps) {
      int r = srow + ps * 32;
      __builtin_amdgcn_global_load_lds(
          (const __attribute__((address_space(1))) void*)(Bt + (size_t)(n0 + r) * KDIM + k0 + sksrc),
          (__attribute__((address_space(3))) void*)(&Bs[buf][r * 64 + skdst]), 16, 0, 0);
    }
  };

  int rl = lane & 15;
  int kb = (lane >> 4) * 8;
  int xorv = (rl & 7) * 8;  // read-side XOR (row&7)*8 elements; row&7 == rl&7

  constexpr int NT = KDIM / 64;  // 36
  stage(0, 0);
  stage(1, 1);

  auto kstep = [&](int kt, int cur, int stg, bool dostage, bool last) {
    // wait: this iter's 6 loads (oldest in queue) done; next tile's stay in flight
    if (last) asm volatile("s_waitcnt vmcnt(0)" ::: "memory");
    else      asm volatile("s_waitcnt vmcnt(6)" ::: "memory");
    __builtin_amdgcn_s_barrier();   // all waves' stores to buf[cur] now visible
    if (dostage) stage(stg, kt + 2);
    const bf16* as = As[cur];
    const bf16* bs = Bs[cur];
#pragma unroll
    for (int kh = 0; kh < 2; ++kh) {
      int kc = (kh * 32 + kb) ^ xorv;
      bf16x8 af[4], bfr[2];
#pragma unroll
      for (int i = 0; i < 4; ++i)
        af[i] = *(const bf16x8*)(as + (wr + i * 16 + rl) * 64 + kc);
#pragma unroll
      for (int j = 0; j < 2; ++j)
        bfr[j] = *(const bf16x8*)(bs + (wc + j * 16 + rl) * 64 + kc);
#pragma unroll
      for (int i = 0; i < 4; ++i)
#pragma unroll
        for (int j = 0; j < 2; ++j)
          acc[i][j] = __builtin_amdgcn_mfma_f32_16x16x32_bf16(af[i], bfr[j], acc[i][j], 0, 0, 0);
    }
  };

  for (int kt = 0; kt < NT - 3; kt += 3) {  // kt = 0..30, iters 0..32
    kstep(kt + 0, 0, 2, true, false);
    kstep(kt + 1, 1, 0, true, false);
    kstep(kt + 2, 2, 1, true, false);
  }
  kstep(NT - 3, 0, 2, true, false);   // iter 33, stages tile 35
  kstep(NT - 2, 1, 0, false, false);  // iter 34
  kstep(NT - 1, 2, 0, false, true);   // iter 35, vmcnt(0)

  // epilogue: C/D layout col=lane&15, row=(lane>>4)*4+r. Fused GN partials.
  int cl = lane & 15, rg = (lane >> 4) * 4;
  int b = n0 >> 12;  // BN=64 n-tile lies within one image
#pragma unroll
  for (int i = 0; i < 4; ++i) {
    int obase = m0 + wr + i * 16;      // multiple of 16, group-aligned
    int ob = obase + rg;
    float s = 0.f, s2 = 0.f;
#pragma unroll
    for (int j = 0; j < 2; ++j) {
      int nn = n0 + wc + j * 16 + cl;
#pragma unroll
      for (int r = 0; r < 4; ++r) {
        float yv = acc[i][j][r] + bias[ob + r];
        Y[(size_t)(ob + r) * NTOT + nn] = yv;
        s += yv;
        s2 = fmaf(yv, yv, s2);
      }
    }
    // reduce within each 32-lane half (covers one 8-ch group each)
#pragma unroll
    for (int mk = 1; mk <= 16; mk <<= 1) {
      s += __shfl_xor(s, mk);
      s2 += __shfl_xor(s2, mk);
    }
    if ((lane & 31) == 0) {
      int g = (obase >> 3) + (lane >> 5);
      atomicAdd(&gsum[b * 32 + g], s);
      atomicAdd(&gsq[b * 32 + g], s2);
    }
  }
}

// ---------- 6. apply norm + relu, write out[b][o][hw] (stats inline) ----------
__global__ __launch_bounds__(256) void k_apply(const float* __restrict__ Y,
                                               const float* __restrict__ gsum,
                                               const float* __restrict__ gsq,
                                               const float* __restrict__ gamma,
                                               const float* __restrict__ beta,
                                               float* __restrict__ out) {
  int i = blockIdx.x * 256 + threadIdx.x;  // vec4 id, 1048576 total
  int hw4 = i & 1023;
  int o = (i >> 10) & 255;
  int b = i >> 18;
  int g = o >> 3;
  float mu = gsum[b * 32 + g] * (1.f / 32768.f);
  float var = gsq[b * 32 + g] * (1.f / 32768.f) - mu * mu;
  float rs = rsqrtf(var + 1e-5f);
  float s = rs * gamma[o];
  float t = beta[o] - mu * s;
  f32x4 v = *(const f32x4*)(Y + (size_t)o * NTOT + b * HW + hw4 * 4);
  f32x4 r;
#pragma unroll
  for (int k = 0; k < 4; ++k) r[k] = fmaxf(v[k] * s + t, 0.f);
  *(f32x4*)(out + (size_t)i * 4) = r;
}

extern "C" void kernel_launch(void* const* d_in, const int* in_sizes, int n_in,
                              void* d_out, int out_size, void* d_ws, size_t ws_size,
                              hipStream_t stream) {
  const float* x = (const float*)d_in[0];
  const float* w_off = (const float*)d_in[1];
  const float* b_off = (const float*)d_in[2];
  const float* w = (const float*)d_in[3];
  const float* bias = (const float*)d_in[4];
  const float* gamma = (const float*)d_in[5];
  const float* beta = (const float*)d_in[6];
  float* out = (float*)d_out;
  char* ws = (char*)d_ws;

  float* xt = (float*)(ws);                                  // 16,777,216 B
  float* offb = (float*)(ws + 16777216);                     //  1,179,648 B
  bf16* Abf = (bf16*)(ws + 16777216 + 1179648);              //  1,179,648 B
  bf16* colsT = (bf16*)(ws + 16777216 + 2 * 1179648);        // 75,497,472 B
  float* Y = (float*)(ws + 16777216 + 2 * 1179648 + 75497472);  // 16,777,216 B
  float* gsum = (float*)(ws + 2 * 16777216 + 2 * 1179648 + 75497472);  // 512 B
  float* gsq = gsum + 128;                                             // 512 B

  // scratch for the offset conv, aliased into the colsT region (dead until
  // k_gather, which runs after k_offreduce and fully overwrites it)
  float* wt = (float*)colsT;                       // 165,888 B
  float* part = (float*)((char*)colsT + 262144);   // 9,437,184 B

  hipMemsetAsync(gsum, 0, 2 * 128 * sizeof(float), stream);
  k_transpose<<<4096, 256, 0, stream>>>(x, xt);
  k_prepwt<<<162, 256, 0, stream>>>(w_off, wt);
  k_convoff2<<<512, 256, 0, stream>>>(x, wt, part);
  k_offreduce<<<288, 256, 0, stream>>>(part, b_off, offb);
  k_prepw<<<2304, 256, 0, stream>>>(w, Abf);
  k_gather<<<4096, 256, 0, stream>>>(xt, offb, colsT);
  k_gemm<<<512, 256, 0, stream>>>(Abf, colsT, bias, Y, gsum, gsq);
  k_apply<<<4096, 256, 0, stream>>>(Y, gsum, gsq, gamma, beta, out);
}

// Round 8
// 139.289 us; speedup vs baseline: 1.1279x; 1.0254x over previous
//
#include <hip/hip_runtime.h>
#include <hip/hip_bf16.h>

using bf16 = __hip_bfloat16;
typedef __attribute__((ext_vector_type(4))) float f32x4;
typedef __attribute__((ext_vector_type(2))) float f32x2;
typedef __attribute__((ext_vector_type(8))) __bf16 bf16x8;
typedef __attribute__((ext_vector_type(4))) __bf16 bf16x4;

#define CIN 256
#define COUT 256
#define HW 4096
#define NB 4
#define NTOT 16384   // NB*HW
#define KDIM 2304    // CIN*9

// ---------- 1. transpose x: NCHW -> NHWC ----------
__global__ __launch_bounds__(256) void k_transpose(const float* __restrict__ x,
                                                   float* __restrict__ xt) {
  __shared__ float t[32][33];
  int bid = blockIdx.x;            // 4 * 128 * 8
  int ct = bid & 7;
  int hwt = (bid >> 3) & 127;
  int b = bid >> 10;
  int tx = threadIdx.x & 31, ty = threadIdx.x >> 5;
  int c0 = ct * 32, hw0 = hwt * 32;
  const float* xb = x + (size_t)b * CIN * HW;
#pragma unroll
  for (int i = 0; i < 32; i += 8)
    t[ty + i][tx] = xb[(size_t)(c0 + ty + i) * HW + hw0 + tx];
  __syncthreads();
  float* xo = xt + ((size_t)b * HW + hw0) * CIN + c0;
#pragma unroll
  for (int i = 0; i < 32; i += 8)
    xo[(size_t)(ty + i) * CIN + tx] = t[tx][ty + i];
}

// ---------- 2a. weight transpose for offset conv: wof[oc][c][p] -> wt[c][p][oc]
__global__ __launch_bounds__(256) void k_prepwt(const float* __restrict__ wof,
                                                float* __restrict__ wt) {
  int i = blockIdx.x * 256 + threadIdx.x;  // (c*9+p)*18 + oc, total 41472
  if (i >= 18 * CIN * 9) return;
  int oc = i % 18;
  int cp = i / 18;
  int c = cp / 9, p = cp % 9;
  wt[i] = wof[((size_t)oc * CIN + c) * 9 + p];
}

// ---------- 2b. offset conv partials: LDS-tiled, channel-chunked ----------
// grid: b(4) x rowtile(16) x cchunk(8); block = 4 rows x 64 cols
__global__ __launch_bounds__(256) void k_convoff2(const float* __restrict__ x,
                                                  const float* __restrict__ wt,
                                                  float* __restrict__ part) {
  __shared__ float lds[8][6][68];  // [ch][row][2+col], cols 1 & 66 are zero halo
  int bid = blockIdx.x;
  int chunk = bid & 7;
  int rt = (bid >> 3) & 15;
  int b = bid >> 7;
  int tid = threadIdx.x;
  int wq = tid & 63, r = tid >> 6;
  int h0 = rt * 4;
  int c0 = chunk * 32;

  // zero the halo columns once (stay zero across stages)
  if (tid < 96) {
    int cl = tid / 12, rem = tid % 12;
    lds[cl][rem >> 1][(rem & 1) ? 66 : 1] = 0.f;
  }

  float acc[18];
#pragma unroll
  for (int o = 0; o < 18; ++o) acc[o] = 0.f;

  int ch = tid >> 5, l32 = tid & 31;
  const float* xb = x + (size_t)b * CIN * HW;

  for (int cs = 0; cs < 32; cs += 8) {
    __syncthreads();
    // stage 8 channels x 6 rows x 64 cols (coalesced float2)
    const float* xp = xb + (size_t)(c0 + cs + ch) * HW;
#pragma unroll
    for (int r6 = 0; r6 < 6; ++r6) {
      int hh = h0 - 1 + r6;
      f32x2 v = {0.f, 0.f};
      if ((unsigned)hh < 64u) v = *(const f32x2*)(xp + hh * 64 + l32 * 2);
      *(f32x2*)&lds[ch][r6][2 + l32 * 2] = v;
    }
    __syncthreads();
#pragma unroll
    for (int cl = 0; cl < 8; ++cl) {
      int c = c0 + cs + cl;  // uniform
      const float* wc = wt + (size_t)c * 9 * 18;  // uniform -> s_load
      float xv[9];
#pragma unroll
      for (int ky = 0; ky < 3; ++ky)
#pragma unroll
        for (int kx = 0; kx < 3; ++kx)
          xv[ky * 3 + kx] = lds[cl][r + ky][1 + wq + kx];
#pragma unroll
      for (int p = 0; p < 9; ++p)
#pragma unroll
        for (int o = 0; o < 18; ++o)
          acc[o] = fmaf(xv[p], wc[p * 18 + o], acc[o]);
    }
  }

  float* pp = part + (size_t)chunk * (NB * 18 * HW) + (size_t)b * 18 * HW +
              (h0 + r) * 64 + wq;
#pragma unroll
  for (int o = 0; o < 18; ++o) pp[(size_t)o * HW] = acc[o];
}

// ---------- 2c. reduce channel-chunk partials + bias -> off[b][18][hw] ----------
__global__ __launch_bounds__(256) void k_offreduce(const float* __restrict__ part,
                                                   const float* __restrict__ boff,
                                                   float* __restrict__ off) {
  int i = blockIdx.x * 256 + threadIdx.x;  // f32x4 idx, total 73728
  int e0 = i * 4;
  int oc = (e0 >> 12) % 18;
  float bo = boff[oc];
  f32x4 s = {bo, bo, bo, bo};
#pragma unroll
  for (int c = 0; c < 8; ++c) s += *(const f32x4*)(part + (size_t)c * (NB * 18 * HW) + e0);
  *(f32x4*)(off + e0) = s;
}

// ---------- 3. weight prep: w[o][c][p] (f32) -> A[o][p*256+c] (bf16) ----------
__global__ __launch_bounds__(256) void k_prepw(const float* __restrict__ w,
                                               bf16* __restrict__ A) {
  int i = blockIdx.x * 256 + threadIdx.x;  // o*2304 + p*256 + c
  int o = i / KDIM, r = i % KDIM;
  int p = r >> 8, c = r & 255;
  A[i] = __float2bfloat16(w[((size_t)o * 256 + c) * 9 + p]);
}

// ---------- 4. bilinear gather -> colsT[n][p*256+c] (bf16) ----------
// one wave per n; lane = 4-channel group (f32x4 loads, bf16x4 stores)
__global__ __launch_bounds__(256) void k_gather(const float* __restrict__ xt,
                                                const float* __restrict__ off,
                                                bf16* __restrict__ colsT) {
  int tid = threadIdx.x;
  int wv = tid >> 6, l = tid & 63;
  int n = blockIdx.x * 4 + wv;
  int hw = n & 4095;
  int b = n >> 12;
  int h = hw >> 6, wq = hw & 63;
  const float* xtb = xt + (size_t)b * HW * CIN + l * 4;
  const float* offb = off + (size_t)b * 18 * HW + hw;
  bf16* outp = colsT + (size_t)n * KDIM + l * 4;
#pragma unroll
  for (int p = 0; p < 9; ++p) {
    float dy = offb[(size_t)(2 * p) * HW];
    float dx = offb[(size_t)(2 * p + 1) * HW];
    float ysf = (float)(h - 1 + p / 3) + dy;
    float xsf = (float)(wq - 1 + p % 3) + dx;
    float y0f = floorf(ysf), x0f = floorf(xsf);
    float wy1 = ysf - y0f, wx1 = xsf - x0f;
    float wy0 = 1.f - wy1, wx0 = 1.f - wx1;
    int y0 = (int)y0f, x0 = (int)x0f;
    int y1 = y0 + 1, x1 = x0 + 1;
    float w00 = wy0 * wx0, w01 = wy0 * wx1, w10 = wy1 * wx0, w11 = wy1 * wx1;
    bool vy0 = (unsigned)y0 < 64u, vy1 = (unsigned)y1 < 64u;
    bool vx0 = (unsigned)x0 < 64u, vx1 = (unsigned)x1 < 64u;
    w00 = (vy0 && vx0) ? w00 : 0.f;
    w01 = (vy0 && vx1) ? w01 : 0.f;
    w10 = (vy1 && vx0) ? w10 : 0.f;
    w11 = (vy1 && vx1) ? w11 : 0.f;
    int y0c = min(max(y0, 0), 63), y1c = min(max(y1, 0), 63);
    int x0c = min(max(x0, 0), 63), x1c = min(max(x1, 0), 63);
    f32x4 v00 = *(const f32x4*)(xtb + (size_t)(y0c * 64 + x0c) * CIN);
    f32x4 v01 = *(const f32x4*)(xtb + (size_t)(y0c * 64 + x1c) * CIN);
    f32x4 v10 = *(const f32x4*)(xtb + (size_t)(y1c * 64 + x0c) * CIN);
    f32x4 v11 = *(const f32x4*)(xtb + (size_t)(y1c * 64 + x1c) * CIN);
    f32x4 v;
#pragma unroll
    for (int k = 0; k < 4; ++k)
      v[k] = w00 * v00[k] + w01 * v01[k] + w10 * v10[k] + w11 * v11[k];
    bf16x4 o;
#pragma unroll
    for (int k = 0; k < 4; ++k) o[k] = (__bf16)v[k];
    *(bf16x4*)(outp + p * 256) = o;
  }
}

// ---------- 5. GEMM: Y[o][n] = sum_k A[o][k]*colsT[n][k] + bias[o] ----------
// BM=256 (all of M -> B read exactly once), BN=64, BK=64; 256 blocks, 4 waves,
// each wave owns a 64x64 output tile (32 FLOP/B fragment intensity).
// 3-deep LDS ring + counted s_waitcnt vmcnt(10): ~2 K-steps of load cover.
// LDS XOR-swizzled (T2). Fused GN partial sums in epilogue.
__global__ __launch_bounds__(256) void k_gemm(const bf16* __restrict__ A,
                                              const bf16* __restrict__ Bt,
                                              const float* __restrict__ bias,
                                              float* __restrict__ Y,
                                              float* __restrict__ gsum,
                                              float* __restrict__ gsq) {
  __shared__ bf16 As[3][256 * 64];  // 32 KB each
  __shared__ bf16 Bs[3][64 * 64];   //  8 KB each  -> 120 KB total
  int bid = blockIdx.x;
  // bijective XCD swizzle: 256 blocks, 32 consecutive n-tiles per XCD
  int swz = (bid & 7) * 32 + (bid >> 3);
  int n0 = swz * 64;
  int tid = threadIdx.x;
  int lane = tid & 63;
  int wave = tid >> 6;
  int wr = wave * 64;               // per-wave 64x64 output tile, rows wr..wr+63
  f32x4 acc[4][4];
#pragma unroll
  for (int i = 0; i < 4; ++i)
#pragma unroll
    for (int j = 0; j < 4; ++j) acc[i][j] = (f32x4){0.f, 0.f, 0.f, 0.f};

  int srow = tid >> 3;                              // 0..31
  int skdst = (tid & 7) * 8;                        // linear dest k-chunk
  int sksrc = ((tid & 7) ^ ((tid >> 3) & 7)) * 8;   // pre-swizzled source (T2)
  auto stage = [&](int buf, int kt) {               // 10 loads/thread
    int k0 = kt * 64;
#pragma unroll
    for (int ps = 0; ps < 8; ++ps) {
      int r = srow + ps * 32;
      __builtin_amdgcn_global_load_lds(
          (const __attribute__((address_space(1))) void*)(A + (size_t)r * KDIM + k0 + sksrc),
          (__attribute__((address_space(3))) void*)(&As[buf][r * 64 + skdst]), 16, 0, 0);
    }
#pragma unroll
    for (int ps = 0; ps < 2; ++ps) {
      int r = srow + ps * 32;
      __builtin_amdgcn_global_load_lds(
          (const __attribute__((address_space(1))) void*)(Bt + (size_t)(n0 + r) * KDIM + k0 + sksrc),
          (__attribute__((address_space(3))) void*)(&Bs[buf][r * 64 + skdst]), 16, 0, 0);
    }
  };

  int rl = lane & 15;
  int kb = (lane >> 4) * 8;
  int xorv = (rl & 7) * 8;  // read-side XOR (row&7)*8 elements; row&7 == rl&7

  constexpr int NT = KDIM / 64;  // 36
  stage(0, 0);
  stage(1, 1);

  auto kstep = [&](int kt, int cur, int stg, bool dostage, bool last) {
    // wait: this iter's 10 loads (oldest in queue) done; next tile's in flight
    if (last) asm volatile("s_waitcnt vmcnt(0)" ::: "memory");
    else      asm volatile("s_waitcnt vmcnt(10)" ::: "memory");
    __builtin_amdgcn_s_barrier();   // all waves' stores to buf[cur] now visible
    if (dostage) stage(stg, kt + 2);
    const bf16* as = As[cur];
    const bf16* bs = Bs[cur];
#pragma unroll
    for (int kh = 0; kh < 2; ++kh) {
      int kc = (kh * 32 + kb) ^ xorv;
      bf16x8 af[4], bfr[4];
#pragma unroll
      for (int i = 0; i < 4; ++i)
        af[i] = *(const bf16x8*)(as + (wr + i * 16 + rl) * 64 + kc);
#pragma unroll
      for (int j = 0; j < 4; ++j)
        bfr[j] = *(const bf16x8*)(bs + (j * 16 + rl) * 64 + kc);
#pragma unroll
      for (int i = 0; i < 4; ++i)
#pragma unroll
        for (int j = 0; j < 4; ++j)
          acc[i][j] = __builtin_amdgcn_mfma_f32_16x16x32_bf16(af[i], bfr[j], acc[i][j], 0, 0, 0);
    }
  };

  for (int kt = 0; kt < NT - 3; kt += 3) {  // kt = 0..30, steps 0..32
    kstep(kt + 0, 0, 2, true, false);
    kstep(kt + 1, 1, 0, true, false);
    kstep(kt + 2, 2, 1, true, false);
  }
  kstep(NT - 3, 0, 2, true, false);   // step 33, stages tile 35
  kstep(NT - 2, 1, 0, false, false);  // step 34
  kstep(NT - 1, 2, 0, false, true);   // step 35, vmcnt(0)

  // epilogue: C/D layout col=lane&15, row=(lane>>4)*4+r. Fused GN partials.
  int cl = lane & 15, rg = (lane >> 4) * 4;
  int b = n0 >> 12;  // BN=64 n-tile lies within one image
#pragma unroll
  for (int i = 0; i < 4; ++i) {
    int obase = wr + i * 16;           // multiple of 16, group-aligned
    int ob = obase + rg;
    float s = 0.f, s2 = 0.f;
#pragma unroll
    for (int j = 0; j < 4; ++j) {
      int nn = n0 + j * 16 + cl;
#pragma unroll
      for (int r = 0; r < 4; ++r) {
        float yv = acc[i][j][r] + bias[ob + r];
        Y[(size_t)(ob + r) * NTOT + nn] = yv;
        s += yv;
        s2 = fmaf(yv, yv, s2);
      }
    }
    // reduce within each 32-lane half (covers one 8-ch group each)
#pragma unroll
    for (int mk = 1; mk <= 16; mk <<= 1) {
      s += __shfl_xor(s, mk);
      s2 += __shfl_xor(s2, mk);
    }
    if ((lane & 31) == 0) {
      int g = (obase >> 3) + (lane >> 5);
      atomicAdd(&gsum[b * 32 + g], s);
      atomicAdd(&gsq[b * 32 + g], s2);
    }
  }
}

// ---------- 6. apply norm + relu, write out[b][o][hw] (stats inline) ----------
__global__ __launch_bounds__(256) void k_apply(const float* __restrict__ Y,
                                               const float* __restrict__ gsum,
                                               const float* __restrict__ gsq,
                                               const float* __restrict__ gamma,
                                               const float* __restrict__ beta,
                                               float* __restrict__ out) {
  int i = blockIdx.x * 256 + threadIdx.x;  // vec4 id, 1048576 total
  int hw4 = i & 1023;
  int o = (i >> 10) & 255;
  int b = i >> 18;
  int g = o >> 3;
  float mu = gsum[b * 32 + g] * (1.f / 32768.f);
  float var = gsq[b * 32 + g] * (1.f / 32768.f) - mu * mu;
  float rs = rsqrtf(var + 1e-5f);
  float s = rs * gamma[o];
  float t = beta[o] - mu * s;
  f32x4 v = *(const f32x4*)(Y + (size_t)o * NTOT + b * HW + hw4 * 4);
  f32x4 r;
#pragma unroll
  for (int k = 0; k < 4; ++k) r[k] = fmaxf(v[k] * s + t, 0.f);
  *(f32x4*)(out + (size_t)i * 4) = r;
}

extern "C" void kernel_launch(void* const* d_in, const int* in_sizes, int n_in,
                              void* d_out, int out_size, void* d_ws, size_t ws_size,
                              hipStream_t stream) {
  const float* x = (const float*)d_in[0];
  const float* w_off = (const float*)d_in[1];
  const float* b_off = (const float*)d_in[2];
  const float* w = (const float*)d_in[3];
  const float* bias = (const float*)d_in[4];
  const float* gamma = (const float*)d_in[5];
  const float* beta = (const float*)d_in[6];
  float* out = (float*)d_out;
  char* ws = (char*)d_ws;

  float* xt = (float*)(ws);                                  // 16,777,216 B
  float* offb = (float*)(ws + 16777216);                     //  1,179,648 B
  bf16* Abf = (bf16*)(ws + 16777216 + 1179648);              //  1,179,648 B
  bf16* colsT = (bf16*)(ws + 16777216 + 2 * 1179648);        // 75,497,472 B
  float* Y = (float*)(ws + 16777216 + 2 * 1179648 + 75497472);  // 16,777,216 B
  float* gsum = (float*)(ws + 2 * 16777216 + 2 * 1179648 + 75497472);  // 512 B
  float* gsq = gsum + 128;                                             // 512 B

  // scratch for the offset conv, aliased into the colsT region (dead until
  // k_gather, which runs after k_offreduce and fully overwrites it)
  float* wt = (float*)colsT;                       // 165,888 B
  float* part = (float*)((char*)colsT + 262144);   // 9,437,184 B

  hipMemsetAsync(gsum, 0, 2 * 128 * sizeof(float), stream);
  k_transpose<<<4096, 256, 0, stream>>>(x, xt);
  k_prepwt<<<162, 256, 0, stream>>>(w_off, wt);
  k_convoff2<<<512, 256, 0, stream>>>(x, wt, part);
  k_offreduce<<<288, 256, 0, stream>>>(part, b_off, offb);
  k_prepw<<<2304, 256, 0, stream>>>(w, Abf);
  k_gather<<<4096, 256, 0, stream>>>(xt, offb, colsT);
  k_gemm<<<256, 256, 0, stream>>>(Abf, colsT, bias, Y, gsum, gsq);
  k_apply<<<4096, 256, 0, stream>>>(Y, gsum, gsq, gamma, beta, out);
}